// Round 9
// baseline (76.208 us; speedup 1.0000x reference)
//
#include <hip/hip_runtime.h>
#include <math.h>

#define C_ 512
#define HW_ 16384
#define K_ 19
#define M_ 5
#define P_ 95
#define P2 96
#define TPX 64
#define NBLK 1024
#define HL2PI 470.49652900081467f  // 0.5 * 512 * ln(2*pi)

typedef __attribute__((ext_vector_type(8))) short short8;
typedef __attribute__((ext_vector_type(4))) int int4v;
typedef __attribute__((ext_vector_type(4))) float float4v;

// fp32 -> bf16 RNE (prep kernel only; main uses packed cvt)
static __device__ __forceinline__ short f2bf(float f) {
  unsigned u = __builtin_bit_cast(unsigned, f);
  unsigned r = (u + 0x7fffu + ((u >> 16) & 1u)) >> 16;
  return (short)r;
}

// pack 2 floats -> bf16x2 via v_cvt_pk_bf16_f32 (no builtin on gfx950; inline asm)
static __device__ __forceinline__ int pk2(float a, float b) {
  int r;
  asm("v_cvt_pk_bf16_f32 %0, %1, %2" : "=v"(r) : "v"(a), "v"(b));
  return r;
}

// square a bf16x8 fragment in-register: unpack pairs, square, packed-repack
static __device__ __forceinline__ short8 sq8(short8 a) {
  int4v ai = __builtin_bit_cast(int4v, a);
  int4v ri;
#pragma unroll
  for (int j = 0; j < 4; j++) {
    unsigned u = (unsigned)ai[j];
    float lo = __builtin_bit_cast(float, u << 16);
    float hi = __builtin_bit_cast(float, u & 0xffff0000u);
    ri[j] = pk2(lo * lo, hi * hi);
  }
  return __builtin_bit_cast(short8, ri);
}

__device__ __forceinline__ float block_reduce_sum(float v, volatile float* red) {
#pragma unroll
  for (int o = 32; o; o >>= 1) v += __shfl_down(v, o);
  const int lane = threadIdx.x & 63, wv = threadIdx.x >> 6;
  if (lane == 0) red[wv] = v;
  __syncthreads();
  float r = red[0] + red[1] + red[2] + red[3];
  __syncthreads();
  return r;
}

// One block per prototype p. wbf[p][k] bf16 row-major [96][1024]:
//   k <  512: inv_var[c];  k >= 512: mu[c]*inv_var[c]
// cterm[p] = -0.5*q3 - logdet - HL2PI  (fp32)
__global__ __launch_bounds__(256) void prep_kernel(
    const float* __restrict__ means, const float* __restrict__ diag,
    short* __restrict__ wbf, float* __restrict__ cterm) {
  const int p = blockIdx.x;
  const int tid = threadIdx.x;
  __shared__ float red[4];
  if (p >= P_) {  // zero-pad row 95: contributes 0, never selected in max
    for (int c = tid; c < C_; c += 256) {
      wbf[p * 1024 + c] = 0;
      wbf[p * 1024 + 512 + c] = 0;
    }
    if (tid == 0) cterm[p] = 0.f;
    return;
  }
  const float* mrow = means + (size_t)p * C_;
  const float* srow = diag + (size_t)p * C_;
  float m0 = mrow[tid], m1 = mrow[tid + 256];
  float ss = block_reduce_sum(m0 * m0 + m1 * m1, red);
  float rden = 1.f / fmaxf(sqrtf(ss), 1e-12f);  // l2_normalize(means)
  float q3 = 0.f, ld = 0.f;
#pragma unroll
  for (int t = 0; t < 2; t++) {
    int c = tid + t * 256;
    float m = mrow[c], s = srow[c];
    float mu = m * rden;
    float iv = 1.f / (s * s);
    wbf[p * 1024 + c] = f2bf(iv);
    wbf[p * 1024 + 512 + c] = f2bf(mu * iv);
    q3 += mu * mu * iv;
    ld += logf(s);
  }
  q3 = block_reduce_sum(q3, red);
  ld = block_reduce_sum(ld, red);
  if (tid == 0) cterm[p] = -0.5f * q3 - ld - HL2PI;
}

// One block = 64 pixels, 512 threads (8 waves), 2 blocks/CU.
// x lives in registers (xr[64]); v bf16 frags -> LDS (64 KiB).
// u layout: 64 blocks of 1 KiB = [px-tile t_ (4)][ks (16)]; elem (k=c, px) at
// ((t_*16+ks)<<10) | (((c>>3)&3)<<8) | ((px&15)<<4) | ((c&7)<<1).
// MFMA B-frag read for px-tile pxt: ((pxt*16+ksl)<<10) | (lane<<4).
// q1's B-operand (v^2) squared in-register (khalf=0 waves).
__global__ __launch_bounds__(512, 4) void main_kernel(
    const float* __restrict__ x,
    const float* __restrict__ fg, const float* __restrict__ fb,
    const float* __restrict__ mg, const float* __restrict__ mb,
    const short* __restrict__ wbf, const float* __restrict__ cterm,
    float* __restrict__ out) {
  __shared__ __align__(16) char raw[65536];  // v frags; aliased as lp[64][100]
  __shared__ float red0[8 * TPX], red1[8 * TPX];
  __shared__ float meanA[TPX], rstdA[TPX], rnA[TPX], rn2A[TPX];
  __shared__ float mean2A[TPX], rstd2A[TPX];
  __shared__ float mpr[TPX * 20];

  const int tid = threadIdx.x;
  const int px = tid & 63;      // pixel; == lane
  const int part = tid >> 6;    // channel part; == wave index (8 parts x 64 ch)
  const int lane = tid & 63;
  const int n0 = blockIdx.x * TPX;
  const int b = n0 >> 14;
  const int rem = n0 & 16383;
  const int h = rem >> 7;
  const int w0 = rem & 127;  // 0 or 64
  const int cbase = part * 64;
  const float* xp = x + (size_t)b * C_ * HW_ + h * 128 + w0 + px;

  // ---- Phase A: single HBM pass into registers; LN stats ----
  float xr[64];
#pragma unroll
  for (int i = 0; i < 64; i++) xr[i] = xp[(size_t)(cbase + i) * HW_];
  {
    float s = 0.f, q = 0.f;
#pragma unroll
    for (int i = 0; i < 64; i++) {
      s += xr[i];
      q += xr[i] * xr[i];
    }
    red0[part * 64 + px] = s;
    red1[part * 64 + px] = q;
  }
  __syncthreads();
  if (tid < 64) {
    float ss = 0.f, qq = 0.f;
#pragma unroll
    for (int i = 0; i < 8; i++) {
      ss += red0[i * 64 + tid];
      qq += red1[i * 64 + tid];
    }
    float mean = ss * (1.f / C_);
    float var = qq * (1.f / C_) - mean * mean;
    meanA[tid] = mean;
    rstdA[tid] = rsqrtf(var + 1e-5f);
  }
  __syncthreads();

  // ---- Phase B: v = LN(x)*g+b from registers; bf16 frags -> LDS; sum v^2 ----
  {
    const float mean = meanA[px], rstd = rstdA[px];
    const int t_ = px >> 4, lq = px & 15;
    float s2 = 0.f;
#pragma unroll
    for (int t8 = 0; t8 < 8; t8++) {
      const int c0 = cbase + t8 * 8;
      float vv[8];
#pragma unroll
      for (int j = 0; j < 8; j++) {
        float v = fmaf((xr[t8 * 8 + j] - mean) * rstd, fg[c0 + j], fb[c0 + j]);
        s2 += v * v;
        vv[j] = v;
      }
      int4v pk;
#pragma unroll
      for (int j2 = 0; j2 < 4; j2++) pk[j2] = pk2(vv[2 * j2], vv[2 * j2 + 1]);
      *(int4v*)(raw + (((t_ * 16 + (c0 >> 5)) << 10) | (((c0 >> 3) & 3) << 8) | (lq << 4))) = pk;
    }
    red0[part * 64 + px] = s2;
  }
  __syncthreads();
  if (tid < 64) {
    float ss = 0.f;
#pragma unroll
    for (int i = 0; i < 8; i++) ss += red0[i * 64 + tid];
    float rn = 1.f / fmaxf(sqrtf(ss), 1e-12f);  // l2_normalize folded into epilogue
    rnA[tid] = rn;
    rn2A[tid] = rn * rn;
  }
  __syncthreads();

  // ---- MFMA: 8 waves = khalf(2) x pbase(2) x pxpair(2); 3 p-tiles x 2 px-tiles ----
  // khalf=0: B = square(v-frag) (q1, A=iv); khalf=1: B = v-frag (q2, A=mu*iv)
  const int wv = part;
  const int khalf = wv >> 2;
  const int pbase = ((wv >> 1) & 1) * 3;
  const int pxpair = wv & 1;
  const int lm = lane & 15, lk = lane >> 4;
  float4v acc[3][2] = {{}, {}, {}};
  const short* wrow = wbf + (((pbase * 16 + lm) << 10) + (khalf << 9) + (lk << 3));
  const int base0 = (pxpair * 2) * 16384;       // px-tile pxpair*2
  const int base1 = (pxpair * 2 + 1) * 16384;   // px-tile pxpair*2+1
#pragma unroll 4
  for (int ksl = 0; ksl < 16; ksl++) {
    short8 a0 = *(const short8*)(wrow + ksl * 32);
    short8 a1 = *(const short8*)(wrow + 16384 + ksl * 32);
    short8 a2 = *(const short8*)(wrow + 32768 + ksl * 32);
    short8 b0 = *(const short8*)(raw + base0 + (ksl << 10) + (lane << 4));
    short8 b1 = *(const short8*)(raw + base1 + (ksl << 10) + (lane << 4));
    if (khalf == 0) {  // wave-uniform branch
      b0 = sq8(b0);
      b1 = sq8(b1);
    }
    acc[0][0] = __builtin_amdgcn_mfma_f32_16x16x32_bf16(a0, b0, acc[0][0], 0, 0, 0);
    acc[0][1] = __builtin_amdgcn_mfma_f32_16x16x32_bf16(a0, b1, acc[0][1], 0, 0, 0);
    acc[1][0] = __builtin_amdgcn_mfma_f32_16x16x32_bf16(a1, b0, acc[1][0], 0, 0, 0);
    acc[1][1] = __builtin_amdgcn_mfma_f32_16x16x32_bf16(a1, b1, acc[1][1], 0, 0, 0);
    acc[2][0] = __builtin_amdgcn_mfma_f32_16x16x32_bf16(a2, b0, acc[2][0], 0, 0, 0);
    acc[2][1] = __builtin_amdgcn_mfma_f32_16x16x32_bf16(a2, b1, acc[2][1], 0, 0, 0);
  }
  __syncthreads();  // u dead; alias raw as lp[64][100]
  float* lp = (float*)raw;

  // stage 1: khalf0 waves write -0.5*rn2*q1 + ct
  if (khalf == 0) {
#pragma unroll
    for (int i = 0; i < 3; i++) {
      const int prow = (pbase + i) * 16 + lk * 4;
#pragma unroll
      for (int r = 0; r < 4; r++) {
        const float ct = cterm[prow + r];
#pragma unroll
        for (int t2 = 0; t2 < 2; t2++) {
          const int pxx = (pxpair * 2 + t2) * 16 + lm;
          lp[pxx * 100 + prow + r] = fmaf(-0.5f * rn2A[pxx], acc[i][t2][r], ct);
        }
      }
    }
  }
  __syncthreads();
  // stage 2: khalf1 waves add rn*q2
  if (khalf == 1) {
#pragma unroll
    for (int i = 0; i < 3; i++) {
      const int prow = (pbase + i) * 16 + lk * 4;
#pragma unroll
      for (int r = 0; r < 4; r++) {
#pragma unroll
        for (int t2 = 0; t2 < 2; t2++) {
          const int pxx = (pxpair * 2 + t2) * 16 + lm;
          lp[pxx * 100 + prow + r] += rnA[pxx] * acc[i][t2][r];
        }
      }
    }
  }
  __syncthreads();

  // ---- max over M ----
  for (int idx = tid; idx < TPX * K_; idx += 512) {
    const int pxx = idx / K_;
    const int k = idx - pxx * K_;
    const float* row = lp + pxx * 100 + k * M_;
    float mv = row[0];
#pragma unroll
    for (int m = 1; m < M_; m++) mv = fmaxf(mv, row[m]);
    mpr[pxx * 20 + k] = mv;
  }
  __syncthreads();
  // ---- LN over K (two-pass: values ~ -470, var ~ 1e-3) ----
  if (tid < 64) {
    float ss = 0.f;
    for (int k = 0; k < K_; k++) ss += mpr[tid * 20 + k];
    float m2 = ss * (1.f / K_);
    float qq = 0.f;
    for (int k = 0; k < K_; k++) {
      float d = mpr[tid * 20 + k] - m2;
      qq += d * d;
    }
    mean2A[tid] = m2;
    rstd2A[tid] = rsqrtf(qq * (1.f / K_) + 1e-5f);
  }
  __syncthreads();
  // ---- coalesced store (B,K,H,W): 256B rows ----
  float* obase = out + ((size_t)(b * K_) * 128 + h) * 128 + w0;
  for (int idx = tid; idx < TPX * K_; idx += 512) {
    const int k = idx >> 6, pxx = idx & 63;
    float v = fmaf((mpr[pxx * 20 + k] - mean2A[pxx]) * rstd2A[pxx], mg[k], mb[k]);
    obase[(size_t)k * HW_ + pxx] = v;
  }
}

extern "C" void kernel_launch(void* const* d_in, const int* in_sizes, int n_in,
                              void* d_out, int out_size, void* d_ws, size_t ws_size,
                              hipStream_t stream) {
  const float* x = (const float*)d_in[0];
  const float* means = (const float*)d_in[1];
  const float* diag = (const float*)d_in[2];
  const float* fg = (const float*)d_in[3];
  const float* fb = (const float*)d_in[4];
  const float* mg = (const float*)d_in[5];
  const float* mb = (const float*)d_in[6];
  float* out = (float*)d_out;

  short* wbf = (short*)d_ws;                                     // 96*1024*2 B
  float* cterm = (float*)((char*)d_ws + (size_t)P2 * 1024 * 2);  // +96*4 B

  prep_kernel<<<P2, 256, 0, stream>>>(means, diag, wbf, cterm);
  main_kernel<<<NBLK, 512, 0, stream>>>(x, fg, fb, mg, mb, wbf, cterm, out);
}